// Round 8
// baseline (142.264 us; speedup 1.0000x reference)
//
#include <hip/hip_runtime.h>
#include <math.h>

#define NN 25000
#define NE 100000
#define NTILES (NE / 16)   // 6250 edge tiles of 16
#define NBN 98             // ceil(NN/256)
#define NBE 391            // ceil(NE/256)
#define NBP 264            // ceil(2*33792/256)
#define NBC 391            // ceil(NE/256)

typedef __attribute__((ext_vector_type(8))) _Float16 half8;
typedef __attribute__((ext_vector_type(4))) float f32x4;

// ==== zero deg ====
__global__ void __launch_bounds__(256) k_zero(int* __restrict__ deg) {
  int n = blockIdx.x * 256 + threadIdx.x;
  if (n < NN) deg[n] = 0;
}

// ==== fused prep: node encoder | edge encoder | W-pack x2 (fp16) | degree ====
__global__ void __launch_bounds__(256) k_prep(
    const float* __restrict__ x, const float* __restrict__ eattr,
    const int* __restrict__ ei,
    const float* __restrict__ We_node, const float* __restrict__ be_node,
    const float* __restrict__ We_edge, const float* __restrict__ be_edge,
    const float* __restrict__ root1, const float* __restrict__ bias1,
    const float* __restrict__ W1, const float* __restrict__ b1,
    const float* __restrict__ W2, const float* __restrict__ b2,
    float* __restrict__ h0, float* __restrict__ r1pre, float* __restrict__ ea,
    _Float16* __restrict__ Hswz1, _Float16* __restrict__ Hswz2,
    int* __restrict__ deg) {
  int b = blockIdx.x;
  int tid = threadIdx.x;
  if (b < NBN) {
    int n = b * 256 + tid;
    if (n >= NN) return;
    float xv[32], hv[32], rv[32];
#pragma unroll
    for (int i = 0; i < 8; i++) *(float4*)(xv + 4 * i) = *(const float4*)(x + n * 32 + 4 * i);
#pragma unroll
    for (int j = 0; j < 32; j++) hv[j] = be_node[j];
#pragma unroll
    for (int i = 0; i < 32; i++) {
      float xi = xv[i];
#pragma unroll
      for (int j = 0; j < 32; j++) hv[j] += xi * We_node[i * 32 + j];
    }
#pragma unroll
    for (int i = 0; i < 8; i++) *(float4*)(h0 + n * 32 + 4 * i) = *(float4*)(hv + 4 * i);
#pragma unroll
    for (int j = 0; j < 32; j++) rv[j] = bias1[j];
#pragma unroll
    for (int i = 0; i < 32; i++) {
      float hi = hv[i];
#pragma unroll
      for (int j = 0; j < 32; j++) rv[j] += hi * root1[i * 32 + j];
    }
#pragma unroll
    for (int i = 0; i < 8; i++) *(float4*)(r1pre + n * 32 + 4 * i) = *(float4*)(rv + 4 * i);
  } else if (b < NBN + NBE) {
    int e = (b - NBN) * 256 + tid;
    if (e >= NE) return;
    float av[16], ov[32];
#pragma unroll
    for (int i = 0; i < 4; i++) *(float4*)(av + 4 * i) = *(const float4*)(eattr + e * 16 + 4 * i);
#pragma unroll
    for (int j = 0; j < 32; j++) ov[j] = be_edge[j];
#pragma unroll
    for (int k = 0; k < 16; k++) {
      float ak = av[k];
#pragma unroll
      for (int j = 0; j < 32; j++) ov[j] += ak * We_edge[k * 32 + j];
    }
#pragma unroll
    for (int i = 0; i < 8; i++) *(float4*)(ea + e * 32 + 4 * i) = *(float4*)(ov + 4 * i);
  } else if (b < NBN + NBE + NBP) {
    int idx = (b - NBN - NBE) * 256 + tid;
    if (idx >= 2 * 33792) return;
    int sel = idx >= 33792;
    int r = idx - sel * 33792;
    int j = r & 7;
    int l = (r >> 3) & 63;
    int nt = (r >> 9) & 1;
    int t = r >> 10;
    int i = 8 * (l >> 4) + j;
    int o = nt * 16 + (l & 15);
    const float* W = sel ? W2 : W1;
    const float* bb = sel ? b2 : b1;
    float v = (t < 32) ? W[t * 1024 + i * 32 + o] : bb[i * 32 + o];
    (sel ? Hswz2 : Hswz1)[r] = (_Float16)v;
  } else {
    int e = (b - NBN - NBE - NBP) * 256 + tid;
    if (e < NE) atomicAdd(&deg[ei[NE + e]], 1);
  }
}

// ==== scan stage 1: per-block sums of deg ====
__global__ void __launch_bounds__(256) k_scan1(const int* __restrict__ deg,
                                               int* __restrict__ bsum) {
  __shared__ int s[256];
  int tid = threadIdx.x;
  int n = blockIdx.x * 256 + tid;
  s[tid] = (n < NN) ? deg[n] : 0;
  __syncthreads();
  for (int d = 128; d > 0; d >>= 1) {
    if (tid < d) s[tid] += s[tid + d];
    __syncthreads();
  }
  if (tid == 0) bsum[blockIdx.x] = s[0];
}

// ==== scan stage 2: block-local exclusive scan + bsum prefix -> off/cursor ===
__global__ void __launch_bounds__(256) k_scan3(const int* __restrict__ deg,
                                               const int* __restrict__ bsum,
                                               int* __restrict__ off,
                                               int* __restrict__ cursor) {
  __shared__ int sb[128];
  __shared__ int s[256];
  int tid = threadIdx.x;
  if (tid < 128) sb[tid] = (tid < NBN) ? bsum[tid] : 0;
  int n = blockIdx.x * 256 + tid;
  int v = (n < NN) ? deg[n] : 0;
  s[tid] = v;
  __syncthreads();
  for (int d = 1; d < 128; d <<= 1) {
    int t = 0;
    if (tid < 128 && tid >= d) t = sb[tid - d];
    __syncthreads();
    if (tid < 128) sb[tid] += t;
    __syncthreads();
  }
  for (int d = 1; d < 256; d <<= 1) {
    int t = (tid >= d) ? s[tid - d] : 0;
    __syncthreads();
    s[tid] += t;
    __syncthreads();
  }
  int base = (blockIdx.x > 0) ? sb[blockIdx.x - 1] : 0;
  int excl = s[tid] - v + base;
  if (n < NN) { off[n] = excl; cursor[n] = excl; }
}

// ==== CSR fill: slot (csr->edge) and perm (edge->csr) ====
__global__ void k_csr_fill(const int* __restrict__ ei, int* __restrict__ cursor,
                           int* __restrict__ slot, int* __restrict__ perm) {
  int e = blockIdx.x * blockDim.x + threadIdx.x;
  if (e >= NE) return;
  int d = ei[NE + e];
  int p = atomicAdd(&cursor[d], 1);
  slot[p] = e;
  perm[e] = p;
}

// ---- NNConv as MFMA GEMM (fp16 datapath); stores msgbuf in CSR order --------
__global__ void __launch_bounds__(256) k_nnconv_mfma(
    const float* __restrict__ hin, const float* __restrict__ ea,
    const _Float16* __restrict__ Hswz, const int* __restrict__ ei,
    const int* __restrict__ perm, float* __restrict__ msgbuf) {
  extern __shared__ half8 bsh[];   // 32 steps * 2 ntiles * 64 lanes = 64 KB
  int tid = threadIdx.x;
  {
    uint4* s4 = (uint4*)bsh;
    const uint4* g4 = (const uint4*)Hswz;
#pragma unroll
    for (int it = 0; it < 16; it++) s4[tid + 256 * it] = g4[tid + 256 * it];
  }
  __syncthreads();

  int wid = tid >> 6;
  int lane = tid & 63;
  int lrow = lane & 15;        // A row / C col
  int lk8 = (lane >> 4) * 8;   // k-offset of this lane's 8 A elems

  for (int tile = blockIdx.x * 4 + wid; tile < NTILES; tile += gridDim.x * 4) {
    int e0 = tile * 16;
    int e = e0 + lrow;
    int src = ei[e];
    float hf[8];
    *(float4*)(hf)     = *(const float4*)(hin + src * 32 + lk8);
    *(float4*)(hf + 4) = *(const float4*)(hin + src * 32 + lk8 + 4);
    half8 hh;
#pragma unroll
    for (int j = 0; j < 8; j++) hh[j] = (_Float16)hf[j];
    float eav[32];
#pragma unroll
    for (int c = 0; c < 8; c++)
      *(float4*)(eav + 4 * c) = *(const float4*)(ea + e * 32 + 4 * c);

    f32x4 a00 = {0.f, 0.f, 0.f, 0.f}, a01 = a00, a10 = a00, a11 = a00;
#pragma unroll
    for (int t = 0; t < 32; t++) {
      _Float16 eh = (_Float16)eav[t];
      half8 af = hh * eh;          // 4x v_pk_mul_f16
      half8 b0 = bsh[(t * 2 + 0) * 64 + lane];
      half8 b1 = bsh[(t * 2 + 1) * 64 + lane];
      if (t & 1) {
        a01 = __builtin_amdgcn_mfma_f32_16x16x32_f16(af, b0, a01, 0, 0, 0);
        a11 = __builtin_amdgcn_mfma_f32_16x16x32_f16(af, b1, a11, 0, 0, 0);
      } else {
        a00 = __builtin_amdgcn_mfma_f32_16x16x32_f16(af, b0, a00, 0, 0, 0);
        a10 = __builtin_amdgcn_mfma_f32_16x16x32_f16(af, b1, a10, 0, 0, 0);
      }
    }
    // bias K-step (t=32): A = h itself, B from global (L2-cached)
    {
      const half8* gb = (const half8*)Hswz;
      half8 b0 = gb[(32 * 2 + 0) * 64 + lane];
      half8 b1 = gb[(32 * 2 + 1) * 64 + lane];
      a00 = __builtin_amdgcn_mfma_f32_16x16x32_f16(hh, b0, a00, 0, 0, 0);
      a10 = __builtin_amdgcn_mfma_f32_16x16x32_f16(hh, b1, a10, 0, 0, 0);
    }
    f32x4 c0 = a00 + a01;
    f32x4 c1 = a10 + a11;
    int r0 = (lane >> 4) * 4;
#pragma unroll
    for (int r = 0; r < 4; r++) {
      int p = perm[e0 + r0 + r];
      float* mp = msgbuf + p * 32 + lrow;
      mp[0]  = c0[r];
      mp[16] = c1[r];
    }
  }
}

// ---- node pass 1 (2 threads/node): stream CSR msgbuf, pair-exchange, GEMM ---
__global__ void __launch_bounds__(256) k_node1(
    const float* __restrict__ r1pre, const float* __restrict__ msgbuf,
    const int* __restrict__ off, const int* __restrict__ deg,
    const float* __restrict__ Wl, const float* __restrict__ bl,
    const float* __restrict__ Wr, const float* __restrict__ br,
    float* __restrict__ xl, float* __restrict__ xr) {
  int t = blockIdx.x * blockDim.x + threadIdx.x;
  if (t >= 2 * NN) return;
  int n = t >> 1, half = t & 1;
  int c0 = half * 16;
  float hv[16];
  const float* rp = r1pre + n * 32 + c0;
#pragma unroll
  for (int i = 0; i < 4; i++) *(float4*)(hv + 4 * i) = *(const float4*)(rp + 4 * i);
  int o0 = off[n], o1 = o0 + deg[n];
  for (int idx = o0; idx < o1; idx++) {
    const float* mp = msgbuf + idx * 32 + c0;
#pragma unroll
    for (int i = 0; i < 4; i++) {
      float4 mv = *(const float4*)(mp + 4 * i);
      hv[4 * i + 0] += mv.x; hv[4 * i + 1] += mv.y;
      hv[4 * i + 2] += mv.z; hv[4 * i + 3] += mv.w;
    }
  }
#pragma unroll
  for (int j = 0; j < 16; j++) hv[j] = fmaxf(hv[j], 0.f);
  float a0[16], a1[16];
#pragma unroll
  for (int j = 0; j < 16; j++) {
    float o = __shfl_xor(hv[j], 1);
    a0[j] = half ? o : hv[j];
    a1[j] = half ? hv[j] : o;
  }
  const float* W = half ? Wr : Wl;
  const float* bb = half ? br : bl;
  float ov[32];
#pragma unroll
  for (int j = 0; j < 32; j++) ov[j] = bb[j];
#pragma unroll
  for (int i = 0; i < 16; i++) {
    float u = a0[i], v = a1[i];
#pragma unroll
    for (int j = 0; j < 32; j++)
      ov[j] += u * W[i * 32 + j] + v * W[(16 + i) * 32 + j];
  }
  float* dst = (half ? xr : xl) + n * 32;
#pragma unroll
  for (int i = 0; i < 8; i++) *(float4*)(dst + 4 * i) = *(float4*)(ov + 4 * i);
}

// ---- gather xl into CSR order (4 threads/edge, coalesced) -------------------
__global__ void __launch_bounds__(256) k_gather_xls(
    const int* __restrict__ ei, const int* __restrict__ slot,
    const float* __restrict__ xl, float* __restrict__ xls) {
  int t = blockIdx.x * 256 + threadIdx.x;
  if (t >= 4 * NE) return;
  int idx = t >> 2, q = t & 3;
  int s = ei[slot[idx]];
  const float* sp = xl + s * 32 + q * 8;
  float* dp = xls + idx * 32 + q * 8;
  float4 v0 = *(const float4*)(sp);
  float4 v1 = *(const float4*)(sp + 4);
  *(float4*)(dp) = v0;
  *(float4*)(dp + 4) = v1;
}

// ---- GAT node pass (4 threads/node = 1/head): streams xls -------------------
__global__ void __launch_bounds__(256) k_gat_node(
    const float* __restrict__ xl, const float* __restrict__ xr,
    const float* __restrict__ xls,
    const int* __restrict__ off, const int* __restrict__ deg,
    const float* __restrict__ att, const float* __restrict__ bias_gat,
    float* __restrict__ h2) {
  int t = blockIdx.x * blockDim.x + threadIdx.x;
  if (t >= 4 * NN) return;
  int n = t >> 2, hh = t & 3;
  const float* xrp = xr + n * 32 + hh * 8;
  const float* xsp = xl + n * 32 + hh * 8;
  const float* atp = att + hh * 8;
  float xrv[8], attv[8], xself[8];
  *(float4*)(xrv)      = *(const float4*)(xrp);
  *(float4*)(xrv + 4)  = *(const float4*)(xrp + 4);
  *(float4*)(attv)     = *(const float4*)(atp);
  *(float4*)(attv + 4) = *(const float4*)(atp + 4);
  *(float4*)(xself)    = *(const float4*)(xsp);
  *(float4*)(xself + 4)= *(const float4*)(xsp + 4);
  float slg = 0.f;
#pragma unroll
  for (int dg = 0; dg < 8; dg++) {
    float v = xself[dg] + xrv[dg];
    v = (v > 0.f) ? v : 0.2f * v;
    slg += v * attv[dg];
  }
  float mx = slg;
  int o0 = off[n], o1 = o0 + deg[n];
  for (int idx = o0; idx < o1; idx++) {
    const float* xp = xls + idx * 32 + hh * 8;
    float xv[8];
    *(float4*)(xv)     = *(const float4*)(xp);
    *(float4*)(xv + 4) = *(const float4*)(xp + 4);
    float lg = 0.f;
#pragma unroll
    for (int dg = 0; dg < 8; dg++) {
      float v = xv[dg] + xrv[dg];
      v = (v > 0.f) ? v : 0.2f * v;
      lg += v * attv[dg];
    }
    mx = fmaxf(mx, lg);
  }
  float a = __expf(slg - mx);
  float den = a;
  float accv[8];
#pragma unroll
  for (int dg = 0; dg < 8; dg++) accv[dg] = a * xself[dg];
  for (int idx = o0; idx < o1; idx++) {
    const float* xp = xls + idx * 32 + hh * 8;
    float xv[8];
    *(float4*)(xv)     = *(const float4*)(xp);
    *(float4*)(xv + 4) = *(const float4*)(xp + 4);
    float lg = 0.f;
#pragma unroll
    for (int dg = 0; dg < 8; dg++) {
      float v = xv[dg] + xrv[dg];
      v = (v > 0.f) ? v : 0.2f * v;
      lg += v * attv[dg];
    }
    float w = __expf(lg - mx);
    den += w;
#pragma unroll
    for (int dg = 0; dg < 8; dg++) accv[dg] += w * xv[dg];
  }
  float sc = 1.f / (den + 1e-16f);
  float hv[8];
#pragma unroll
  for (int dg = 0; dg < 8; dg++)
    hv[dg] = fmaxf(accv[dg] * sc + bias_gat[hh * 8 + dg], 0.f);
  float* op = h2 + n * 32 + hh * 8;
  *(float4*)(op)     = *(float4*)(hv);
  *(float4*)(op + 4) = *(float4*)(hv + 4);
}

// ---- node pass 2 (2 threads/node): root2 half-GEMM + stream + classifier ----
__global__ void __launch_bounds__(256) k_node2(
    const float* __restrict__ h2, const float* __restrict__ msgbuf,
    const int* __restrict__ off, const int* __restrict__ deg,
    const float* __restrict__ root2, const float* __restrict__ bias2,
    const float* __restrict__ Wlin, const float* __restrict__ blin,
    float* __restrict__ out) {
  int t = blockIdx.x * blockDim.x + threadIdx.x;
  if (t >= 2 * NN) return;
  int n = t >> 1, half = t & 1;
  int c0 = half * 16;
  float h2v[32];
#pragma unroll
  for (int i = 0; i < 8; i++) *(float4*)(h2v + 4 * i) = *(const float4*)(h2 + n * 32 + 4 * i);
  float rv[16];
#pragma unroll
  for (int j = 0; j < 16; j++) rv[j] = bias2[c0 + j];
#pragma unroll
  for (int i = 0; i < 32; i++) {
    float hi = h2v[i];
#pragma unroll
    for (int j = 0; j < 16; j++) rv[j] += hi * root2[i * 32 + c0 + j];
  }
  int o0 = off[n], o1 = o0 + deg[n];
  for (int idx = o0; idx < o1; idx++) {
    const float* mp = msgbuf + idx * 32 + c0;
#pragma unroll
    for (int i = 0; i < 4; i++) {
      float4 mv = *(const float4*)(mp + 4 * i);
      rv[4 * i + 0] += mv.x; rv[4 * i + 1] += mv.y;
      rv[4 * i + 2] += mv.z; rv[4 * i + 3] += mv.w;
    }
  }
#pragma unroll
  for (int j = 0; j < 16; j++) rv[j] = fmaxf(rv[j], 0.f);
  float ov[10];
#pragma unroll
  for (int c = 0; c < 10; c++) ov[c] = 0.f;
#pragma unroll
  for (int j = 0; j < 16; j++) {
    float hj = rv[j];
#pragma unroll
    for (int c = 0; c < 10; c++) ov[c] += hj * Wlin[(c0 + j) * 10 + c];
  }
#pragma unroll
  for (int c = 0; c < 10; c++) ov[c] += __shfl_xor(ov[c], 1);
  if (half == 0) {
#pragma unroll
    for (int c = 0; c < 5; c++) out[n * 10 + c] = ov[c] + blin[c];
  } else {
#pragma unroll
    for (int c = 5; c < 10; c++) out[n * 10 + c] = ov[c] + blin[c];
  }
}

extern "C" void kernel_launch(void* const* d_in, const int* in_sizes, int n_in,
                              void* d_out, int out_size, void* d_ws, size_t ws_size,
                              hipStream_t stream) {
  const float* x         = (const float*)d_in[0];
  const float* edge_attr = (const float*)d_in[1];
  const int*   ei        = (const int*)d_in[2];   // [2,E]: src = ei, dst = ei+NE
  const float* We_node   = (const float*)d_in[3];
  const float* be_node   = (const float*)d_in[4];
  const float* We_edge   = (const float*)d_in[5];
  const float* be_edge   = (const float*)d_in[6];
  const float* W1_nn     = (const float*)d_in[7];
  const float* b1_nn     = (const float*)d_in[8];
  const float* root1     = (const float*)d_in[9];
  const float* bias1     = (const float*)d_in[10];
  const float* Wl        = (const float*)d_in[11];
  const float* bl        = (const float*)d_in[12];
  const float* Wr        = (const float*)d_in[13];
  const float* br        = (const float*)d_in[14];
  const float* att       = (const float*)d_in[15];
  const float* bias_gat  = (const float*)d_in[16];
  const float* W2_nn     = (const float*)d_in[17];
  const float* b2_nn     = (const float*)d_in[18];
  const float* root2     = (const float*)d_in[19];
  const float* bias2     = (const float*)d_in[20];
  const float* Wlin      = (const float*)d_in[21];
  const float* blin      = (const float*)d_in[22];
  float* out = (float*)d_out;

  float* ws = (float*)d_ws;
  float* h0h2  = ws;                 // NN*32 (h0, later h2)
  float* ea    = h0h2 + NN * 32;     // NE*32
  float* r1pre = ea + NE * 32;       // NN*32
  float* xl    = r1pre + NN * 32;    // NN*32
  float* xr    = xl + NN * 32;       // NN*32
  float* msgbuf = xr + NN * 32;      // NE*32 (CSR order; reused conv1/conv2)
  float* xls   = msgbuf + NE * 32;   // NE*32 (xl gathered to CSR order)
  float* fend  = xls + NE * 32;
  _Float16* Hswz1 = (_Float16*)fend;            // 33792 fp16
  _Float16* Hswz2 = (_Float16*)(fend + 17000);  // 33792 fp16
  int* deg    = (int*)(fend + 34000);   // NN
  int* off    = deg + NN;               // NN
  int* cursor = off + NN;               // NN
  int* bsum   = cursor + NN;            // 128
  int* slot   = bsum + 128;             // NE
  int* perm   = slot + NE;              // NE

  const int B = 256;
  k_zero<<<NBN, B, 0, stream>>>(deg);
  k_prep<<<NBN + NBE + NBP + NBC, B, 0, stream>>>(
      x, edge_attr, ei, We_node, be_node, We_edge, be_edge, root1, bias1,
      W1_nn, b1_nn, W2_nn, b2_nn, h0h2, r1pre, ea, Hswz1, Hswz2, deg);
  k_scan1<<<NBN, B, 0, stream>>>(deg, bsum);
  k_scan3<<<NBN, B, 0, stream>>>(deg, bsum, off, cursor);
  k_csr_fill<<<(NE + B - 1) / B, B, 0, stream>>>(ei, cursor, slot, perm);
  k_nnconv_mfma<<<512, B, 65536, stream>>>(h0h2, ea, Hswz1, ei, perm, msgbuf);
  k_node1<<<(2 * NN + B - 1) / B, B, 0, stream>>>(r1pre, msgbuf, off, deg, Wl, bl, Wr, br, xl, xr);
  k_gather_xls<<<(4 * NE + B - 1) / B, B, 0, stream>>>(ei, slot, xl, xls);
  k_gat_node<<<(4 * NN + B - 1) / B, B, 0, stream>>>(xl, xr, xls, off, deg, att, bias_gat, h0h2);
  k_nnconv_mfma<<<512, B, 65536, stream>>>(h0h2, ea, Hswz2, ei, perm, msgbuf);
  k_node2<<<(2 * NN + B - 1) / B, B, 0, stream>>>(h0h2, msgbuf, off, deg, root2, bias2, Wlin, blin, out);
}

// Round 9
// 135.545 us; speedup vs baseline: 1.0496x; 1.0496x over previous
//
#include <hip/hip_runtime.h>
#include <hip/hip_bf16.h>
#include <math.h>

#define NN 25000
#define NE 100000
#define NTILES (NE / 16)   // 6250 edge tiles of 16
#define NBN 98             // ceil(NN/256)
#define NBE 391            // ceil(NE/256)
#define NBP 264            // ceil(2*33792/256)
#define NBC 391            // ceil(NE/256)

typedef __attribute__((ext_vector_type(8))) short short8;
typedef __attribute__((ext_vector_type(4))) float f32x4;

// pack 8 fp32 -> short8 of bf16 via HW packed convert (RTNE)
static __device__ __forceinline__ short8 pack_bf8(const float* p) {
  union { short8 s; unsigned int u[4]; } r;
#pragma unroll
  for (int q = 0; q < 4; q++)
    asm("v_cvt_pk_bf16_f32 %0, %1, %2" : "=v"(r.u[q]) : "v"(p[2 * q]), "v"(p[2 * q + 1]));
  return r.s;
}

// ==== zero deg ====
__global__ void __launch_bounds__(256) k_zero(int* __restrict__ deg) {
  int n = blockIdx.x * 256 + threadIdx.x;
  if (n < NN) deg[n] = 0;
}

// ==== fused prep: node encoder | edge encoder | W-pack x2 | degree count ====
__global__ void __launch_bounds__(256) k_prep(
    const float* __restrict__ x, const float* __restrict__ eattr,
    const int* __restrict__ ei,
    const float* __restrict__ We_node, const float* __restrict__ be_node,
    const float* __restrict__ We_edge, const float* __restrict__ be_edge,
    const float* __restrict__ root1, const float* __restrict__ bias1,
    const float* __restrict__ W1, const float* __restrict__ b1,
    const float* __restrict__ W2, const float* __restrict__ b2,
    float* __restrict__ h0, float* __restrict__ r1pre, float* __restrict__ ea,
    __hip_bfloat16* __restrict__ Bswz1, __hip_bfloat16* __restrict__ Bswz2,
    int* __restrict__ deg) {
  int b = blockIdx.x;
  int tid = threadIdx.x;
  if (b < NBN) {
    int n = b * 256 + tid;
    if (n >= NN) return;
    float xv[32], hv[32], rv[32];
#pragma unroll
    for (int i = 0; i < 8; i++) *(float4*)(xv + 4 * i) = *(const float4*)(x + n * 32 + 4 * i);
#pragma unroll
    for (int j = 0; j < 32; j++) hv[j] = be_node[j];
#pragma unroll
    for (int i = 0; i < 32; i++) {
      float xi = xv[i];
#pragma unroll
      for (int j = 0; j < 32; j++) hv[j] += xi * We_node[i * 32 + j];
    }
#pragma unroll
    for (int i = 0; i < 8; i++) *(float4*)(h0 + n * 32 + 4 * i) = *(float4*)(hv + 4 * i);
#pragma unroll
    for (int j = 0; j < 32; j++) rv[j] = bias1[j];
#pragma unroll
    for (int i = 0; i < 32; i++) {
      float hi = hv[i];
#pragma unroll
      for (int j = 0; j < 32; j++) rv[j] += hi * root1[i * 32 + j];
    }
#pragma unroll
    for (int i = 0; i < 8; i++) *(float4*)(r1pre + n * 32 + 4 * i) = *(float4*)(rv + 4 * i);
  } else if (b < NBN + NBE) {
    int e = (b - NBN) * 256 + tid;
    if (e >= NE) return;
    float av[16], ov[32];
#pragma unroll
    for (int i = 0; i < 4; i++) *(float4*)(av + 4 * i) = *(const float4*)(eattr + e * 16 + 4 * i);
#pragma unroll
    for (int j = 0; j < 32; j++) ov[j] = be_edge[j];
#pragma unroll
    for (int k = 0; k < 16; k++) {
      float ak = av[k];
#pragma unroll
      for (int j = 0; j < 32; j++) ov[j] += ak * We_edge[k * 32 + j];
    }
#pragma unroll
    for (int i = 0; i < 8; i++) *(float4*)(ea + e * 32 + 4 * i) = *(float4*)(ov + 4 * i);
  } else if (b < NBN + NBE + NBP) {
    int idx = (b - NBN - NBE) * 256 + tid;
    if (idx >= 2 * 33792) return;
    int sel = idx >= 33792;
    int r = idx - sel * 33792;
    int j = r & 7;
    int l = (r >> 3) & 63;
    int nt = (r >> 9) & 1;
    int t = r >> 10;
    int i = 8 * (l >> 4) + j;
    int o = nt * 16 + (l & 15);
    const float* W = sel ? W2 : W1;
    const float* bb = sel ? b2 : b1;
    float v = (t < 32) ? W[t * 1024 + i * 32 + o] : bb[i * 32 + o];
    (sel ? Bswz2 : Bswz1)[r] = __float2bfloat16(v);
  } else {
    int e = (b - NBN - NBE - NBP) * 256 + tid;
    if (e < NE) atomicAdd(&deg[ei[NE + e]], 1);
  }
}

// ==== scan stage 1: per-block sums of deg ====
__global__ void __launch_bounds__(256) k_scan1(const int* __restrict__ deg,
                                               int* __restrict__ bsum) {
  __shared__ int s[256];
  int tid = threadIdx.x;
  int n = blockIdx.x * 256 + tid;
  s[tid] = (n < NN) ? deg[n] : 0;
  __syncthreads();
  for (int d = 128; d > 0; d >>= 1) {
    if (tid < d) s[tid] += s[tid + d];
    __syncthreads();
  }
  if (tid == 0) bsum[blockIdx.x] = s[0];
}

// ==== scan stage 2: block-local exclusive scan + bsum prefix -> off/cursor ===
__global__ void __launch_bounds__(256) k_scan3(const int* __restrict__ deg,
                                               const int* __restrict__ bsum,
                                               int* __restrict__ off,
                                               int* __restrict__ cursor) {
  __shared__ int sb[128];
  __shared__ int s[256];
  int tid = threadIdx.x;
  if (tid < 128) sb[tid] = (tid < NBN) ? bsum[tid] : 0;
  int n = blockIdx.x * 256 + tid;
  int v = (n < NN) ? deg[n] : 0;
  s[tid] = v;
  __syncthreads();
  for (int d = 1; d < 128; d <<= 1) {
    int t = 0;
    if (tid < 128 && tid >= d) t = sb[tid - d];
    __syncthreads();
    if (tid < 128) sb[tid] += t;
    __syncthreads();
  }
  for (int d = 1; d < 256; d <<= 1) {
    int t = (tid >= d) ? s[tid - d] : 0;
    __syncthreads();
    s[tid] += t;
    __syncthreads();
  }
  int base = (blockIdx.x > 0) ? sb[blockIdx.x - 1] : 0;
  int excl = s[tid] - v + base;
  if (n < NN) { off[n] = excl; cursor[n] = excl; }
}

// ==== CSR fill: slot (csr->edge) and perm (edge->csr) ====
__global__ void k_csr_fill(const int* __restrict__ ei, int* __restrict__ cursor,
                           int* __restrict__ slot, int* __restrict__ perm) {
  int e = blockIdx.x * blockDim.x + threadIdx.x;
  if (e >= NE) return;
  int d = ei[NE + e];
  int p = atomicAdd(&cursor[d], 1);
  slot[p] = e;
  perm[e] = p;
}

// ---- NNConv as MFMA GEMM (bf16); 512-thread blocks -> 16 waves/CU -----------
__global__ void __launch_bounds__(512) k_nnconv_mfma(
    const float* __restrict__ hin, const float* __restrict__ ea,
    const __hip_bfloat16* __restrict__ Bswz, const int* __restrict__ ei,
    const int* __restrict__ perm, float* __restrict__ msgbuf) {
  extern __shared__ short8 bsh[];   // 32 steps * 2 ntiles * 64 lanes = 64 KB
  int tid = threadIdx.x;
  {
    uint4* s4 = (uint4*)bsh;
    const uint4* g4 = (const uint4*)Bswz;
#pragma unroll
    for (int it = 0; it < 8; it++) s4[tid + 512 * it] = g4[tid + 512 * it];
  }
  __syncthreads();

  int wid = tid >> 6;          // 0..7
  int lane = tid & 63;
  int lrow = lane & 15;        // A row / C col
  int lk8 = (lane >> 4) * 8;   // k-offset of this lane's 8 A elems

  for (int tile = blockIdx.x * 8 + wid; tile < NTILES; tile += gridDim.x * 8) {
    int e0 = tile * 16;
    int e = e0 + lrow;
    int src = ei[e];
    float hf[8];
    *(float4*)(hf)     = *(const float4*)(hin + src * 32 + lk8);
    *(float4*)(hf + 4) = *(const float4*)(hin + src * 32 + lk8 + 4);
    float eav[32];
#pragma unroll
    for (int c = 0; c < 8; c++)
      *(float4*)(eav + 4 * c) = *(const float4*)(ea + e * 32 + 4 * c);
    short8 af_bias = pack_bf8(hf);   // bias-step A frag

    f32x4 a00 = {0.f, 0.f, 0.f, 0.f}, a01 = a00, a10 = a00, a11 = a00;
#pragma unroll
    for (int t = 0; t < 32; t++) {
      float et = eav[t];
      float pr[8];
#pragma unroll
      for (int j = 0; j < 8; j++) pr[j] = et * hf[j];
      short8 af = pack_bf8(pr);
      short8 b0 = bsh[(t * 2 + 0) * 64 + lane];
      short8 b1 = bsh[(t * 2 + 1) * 64 + lane];
      if (t & 1) {
        a01 = __builtin_amdgcn_mfma_f32_16x16x32_bf16(af, b0, a01, 0, 0, 0);
        a11 = __builtin_amdgcn_mfma_f32_16x16x32_bf16(af, b1, a11, 0, 0, 0);
      } else {
        a00 = __builtin_amdgcn_mfma_f32_16x16x32_bf16(af, b0, a00, 0, 0, 0);
        a10 = __builtin_amdgcn_mfma_f32_16x16x32_bf16(af, b1, a10, 0, 0, 0);
      }
    }
    // bias K-step (t=32): A = h itself, B from global (L2-cached)
    {
      const short8* gb = (const short8*)Bswz;
      short8 b0 = gb[(32 * 2 + 0) * 64 + lane];
      short8 b1 = gb[(32 * 2 + 1) * 64 + lane];
      a00 = __builtin_amdgcn_mfma_f32_16x16x32_bf16(af_bias, b0, a00, 0, 0, 0);
      a10 = __builtin_amdgcn_mfma_f32_16x16x32_bf16(af_bias, b1, a10, 0, 0, 0);
    }
    f32x4 c0 = a00 + a01;
    f32x4 c1 = a10 + a11;
    int r0 = (lane >> 4) * 4;
#pragma unroll
    for (int r = 0; r < 4; r++) {
      int p = perm[e0 + r0 + r];
      float* mp = msgbuf + p * 32 + lrow;
      mp[0]  = c0[r];
      mp[16] = c1[r];
    }
  }
}

// ---- node pass 1 (2 threads/node): stream CSR msgbuf, pair-exchange, GEMM ---
__global__ void __launch_bounds__(256) k_node1(
    const float* __restrict__ r1pre, const float* __restrict__ msgbuf,
    const int* __restrict__ off, const int* __restrict__ deg,
    const float* __restrict__ Wl, const float* __restrict__ bl,
    const float* __restrict__ Wr, const float* __restrict__ br,
    float* __restrict__ xl, float* __restrict__ xr) {
  int t = blockIdx.x * blockDim.x + threadIdx.x;
  if (t >= 2 * NN) return;
  int n = t >> 1, half = t & 1;
  int c0 = half * 16;
  float hv[16];
  const float* rp = r1pre + n * 32 + c0;
#pragma unroll
  for (int i = 0; i < 4; i++) *(float4*)(hv + 4 * i) = *(const float4*)(rp + 4 * i);
  int o0 = off[n], o1 = o0 + deg[n];
  for (int idx = o0; idx < o1; idx++) {
    const float* mp = msgbuf + idx * 32 + c0;
#pragma unroll
    for (int i = 0; i < 4; i++) {
      float4 mv = *(const float4*)(mp + 4 * i);
      hv[4 * i + 0] += mv.x; hv[4 * i + 1] += mv.y;
      hv[4 * i + 2] += mv.z; hv[4 * i + 3] += mv.w;
    }
  }
#pragma unroll
  for (int j = 0; j < 16; j++) hv[j] = fmaxf(hv[j], 0.f);
  float a0[16], a1[16];
#pragma unroll
  for (int j = 0; j < 16; j++) {
    float o = __shfl_xor(hv[j], 1);
    a0[j] = half ? o : hv[j];
    a1[j] = half ? hv[j] : o;
  }
  const float* W = half ? Wr : Wl;
  const float* bb = half ? br : bl;
  float ov[32];
#pragma unroll
  for (int j = 0; j < 32; j++) ov[j] = bb[j];
#pragma unroll
  for (int i = 0; i < 16; i++) {
    float u = a0[i], v = a1[i];
#pragma unroll
    for (int j = 0; j < 32; j++)
      ov[j] += u * W[i * 32 + j] + v * W[(16 + i) * 32 + j];
  }
  float* dst = (half ? xr : xl) + n * 32;
#pragma unroll
  for (int i = 0; i < 8; i++) *(float4*)(dst + 4 * i) = *(float4*)(ov + 4 * i);
}

// ---- gather xl into CSR order (4 threads/edge, coalesced) -------------------
__global__ void __launch_bounds__(256) k_gather_xls(
    const int* __restrict__ ei, const int* __restrict__ slot,
    const float* __restrict__ xl, float* __restrict__ xls) {
  int t = blockIdx.x * 256 + threadIdx.x;
  if (t >= 4 * NE) return;
  int idx = t >> 2, q = t & 3;
  int s = ei[slot[idx]];
  const float* sp = xl + s * 32 + q * 8;
  float* dp = xls + idx * 32 + q * 8;
  float4 v0 = *(const float4*)(sp);
  float4 v1 = *(const float4*)(sp + 4);
  *(float4*)(dp) = v0;
  *(float4*)(dp + 4) = v1;
}

// ---- GAT node pass (4 threads/node = 1/head): streams xls -------------------
__global__ void __launch_bounds__(256) k_gat_node(
    const float* __restrict__ xl, const float* __restrict__ xr,
    const float* __restrict__ xls,
    const int* __restrict__ off, const int* __restrict__ deg,
    const float* __restrict__ att, const float* __restrict__ bias_gat,
    float* __restrict__ h2) {
  int t = blockIdx.x * blockDim.x + threadIdx.x;
  if (t >= 4 * NN) return;
  int n = t >> 2, hh = t & 3;
  const float* xrp = xr + n * 32 + hh * 8;
  const float* xsp = xl + n * 32 + hh * 8;
  const float* atp = att + hh * 8;
  float xrv[8], attv[8], xself[8];
  *(float4*)(xrv)      = *(const float4*)(xrp);
  *(float4*)(xrv + 4)  = *(const float4*)(xrp + 4);
  *(float4*)(attv)     = *(const float4*)(atp);
  *(float4*)(attv + 4) = *(const float4*)(atp + 4);
  *(float4*)(xself)    = *(const float4*)(xsp);
  *(float4*)(xself + 4)= *(const float4*)(xsp + 4);
  float slg = 0.f;
#pragma unroll
  for (int dg = 0; dg < 8; dg++) {
    float v = xself[dg] + xrv[dg];
    v = (v > 0.f) ? v : 0.2f * v;
    slg += v * attv[dg];
  }
  float mx = slg;
  int o0 = off[n], o1 = o0 + deg[n];
  for (int idx = o0; idx < o1; idx++) {
    const float* xp = xls + idx * 32 + hh * 8;
    float xv[8];
    *(float4*)(xv)     = *(const float4*)(xp);
    *(float4*)(xv + 4) = *(const float4*)(xp + 4);
    float lg = 0.f;
#pragma unroll
    for (int dg = 0; dg < 8; dg++) {
      float v = xv[dg] + xrv[dg];
      v = (v > 0.f) ? v : 0.2f * v;
      lg += v * attv[dg];
    }
    mx = fmaxf(mx, lg);
  }
  float a = __expf(slg - mx);
  float den = a;
  float accv[8];
#pragma unroll
  for (int dg = 0; dg < 8; dg++) accv[dg] = a * xself[dg];
  for (int idx = o0; idx < o1; idx++) {
    const float* xp = xls + idx * 32 + hh * 8;
    float xv[8];
    *(float4*)(xv)     = *(const float4*)(xp);
    *(float4*)(xv + 4) = *(const float4*)(xp + 4);
    float lg = 0.f;
#pragma unroll
    for (int dg = 0; dg < 8; dg++) {
      float v = xv[dg] + xrv[dg];
      v = (v > 0.f) ? v : 0.2f * v;
      lg += v * attv[dg];
    }
    float w = __expf(lg - mx);
    den += w;
#pragma unroll
    for (int dg = 0; dg < 8; dg++) accv[dg] += w * xv[dg];
  }
  float sc = 1.f / (den + 1e-16f);
  float hv[8];
#pragma unroll
  for (int dg = 0; dg < 8; dg++)
    hv[dg] = fmaxf(accv[dg] * sc + bias_gat[hh * 8 + dg], 0.f);
  float* op = h2 + n * 32 + hh * 8;
  *(float4*)(op)     = *(float4*)(hv);
  *(float4*)(op + 4) = *(float4*)(hv + 4);
}

// ---- node pass 2 (2 threads/node): root2 half-GEMM + stream + classifier ----
__global__ void __launch_bounds__(256) k_node2(
    const float* __restrict__ h2, const float* __restrict__ msgbuf,
    const int* __restrict__ off, const int* __restrict__ deg,
    const float* __restrict__ root2, const float* __restrict__ bias2,
    const float* __restrict__ Wlin, const float* __restrict__ blin,
    float* __restrict__ out) {
  int t = blockIdx.x * blockDim.x + threadIdx.x;
  if (t >= 2 * NN) return;
  int n = t >> 1, half = t & 1;
  int c0 = half * 16;
  float h2v[32];
#pragma unroll
  for (int i = 0; i < 8; i++) *(float4*)(h2v + 4 * i) = *(const float4*)(h2 + n * 32 + 4 * i);
  float rv[16];
#pragma unroll
  for (int j = 0; j < 16; j++) rv[j] = bias2[c0 + j];
#pragma unroll
  for (int i = 0; i < 32; i++) {
    float hi = h2v[i];
#pragma unroll
    for (int j = 0; j < 16; j++) rv[j] += hi * root2[i * 32 + c0 + j];
  }
  int o0 = off[n], o1 = o0 + deg[n];
  for (int idx = o0; idx < o1; idx++) {
    const float* mp = msgbuf + idx * 32 + c0;
#pragma unroll
    for (int i = 0; i < 4; i++) {
      float4 mv = *(const float4*)(mp + 4 * i);
      rv[4 * i + 0] += mv.x; rv[4 * i + 1] += mv.y;
      rv[4 * i + 2] += mv.z; rv[4 * i + 3] += mv.w;
    }
  }
#pragma unroll
  for (int j = 0; j < 16; j++) rv[j] = fmaxf(rv[j], 0.f);
  float ov[10];
#pragma unroll
  for (int c = 0; c < 10; c++) ov[c] = 0.f;
#pragma unroll
  for (int j = 0; j < 16; j++) {
    float hj = rv[j];
#pragma unroll
    for (int c = 0; c < 10; c++) ov[c] += hj * Wlin[(c0 + j) * 10 + c];
  }
#pragma unroll
  for (int c = 0; c < 10; c++) ov[c] += __shfl_xor(ov[c], 1);
  if (half == 0) {
#pragma unroll
    for (int c = 0; c < 5; c++) out[n * 10 + c] = ov[c] + blin[c];
  } else {
#pragma unroll
    for (int c = 5; c < 10; c++) out[n * 10 + c] = ov[c] + blin[c];
  }
}

extern "C" void kernel_launch(void* const* d_in, const int* in_sizes, int n_in,
                              void* d_out, int out_size, void* d_ws, size_t ws_size,
                              hipStream_t stream) {
  const float* x         = (const float*)d_in[0];
  const float* edge_attr = (const float*)d_in[1];
  const int*   ei        = (const int*)d_in[2];   // [2,E]: src = ei, dst = ei+NE
  const float* We_node   = (const float*)d_in[3];
  const float* be_node   = (const float*)d_in[4];
  const float* We_edge   = (const float*)d_in[5];
  const float* be_edge   = (const float*)d_in[6];
  const float* W1_nn     = (const float*)d_in[7];
  const float* b1_nn     = (const float*)d_in[8];
  const float* root1     = (const float*)d_in[9];
  const float* bias1     = (const float*)d_in[10];
  const float* Wl        = (const float*)d_in[11];
  const float* bl        = (const float*)d_in[12];
  const float* Wr        = (const float*)d_in[13];
  const float* br        = (const float*)d_in[14];
  const float* att       = (const float*)d_in[15];
  const float* bias_gat  = (const float*)d_in[16];
  const float* W2_nn     = (const float*)d_in[17];
  const float* b2_nn     = (const float*)d_in[18];
  const float* root2     = (const float*)d_in[19];
  const float* bias2     = (const float*)d_in[20];
  const float* Wlin      = (const float*)d_in[21];
  const float* blin      = (const float*)d_in[22];
  float* out = (float*)d_out;

  float* ws = (float*)d_ws;
  float* h0h2  = ws;                 // NN*32 (h0, later h2)
  float* ea    = h0h2 + NN * 32;     // NE*32
  float* r1pre = ea + NE * 32;       // NN*32
  float* xl    = r1pre + NN * 32;    // NN*32
  float* xr    = xl + NN * 32;       // NN*32
  float* msgbuf = xr + NN * 32;      // NE*32 (CSR order; reused conv1/conv2)
  float* xls   = msgbuf + NE * 32;   // NE*32 (xl gathered to CSR order)
  float* fend  = xls + NE * 32;
  __hip_bfloat16* Bswz1 = (__hip_bfloat16*)fend;            // 33792 bf16
  __hip_bfloat16* Bswz2 = (__hip_bfloat16*)(fend + 17000);  // 33792 bf16
  int* deg    = (int*)(fend + 34000);   // NN
  int* off    = deg + NN;               // NN
  int* cursor = off + NN;               // NN
  int* bsum   = cursor + NN;            // 128
  int* slot   = bsum + 128;             // NE
  int* perm   = slot + NE;              // NE

  const int B = 256;
  k_zero<<<NBN, B, 0, stream>>>(deg);
  k_prep<<<NBN + NBE + NBP + NBC, B, 0, stream>>>(
      x, edge_attr, ei, We_node, be_node, We_edge, be_edge, root1, bias1,
      W1_nn, b1_nn, W2_nn, b2_nn, h0h2, r1pre, ea, Bswz1, Bswz2, deg);
  k_scan1<<<NBN, B, 0, stream>>>(deg, bsum);
  k_scan3<<<NBN, B, 0, stream>>>(deg, bsum, off, cursor);
  k_csr_fill<<<(NE + B - 1) / B, B, 0, stream>>>(ei, cursor, slot, perm);
  k_nnconv_mfma<<<256, 512, 65536, stream>>>(h0h2, ea, Bswz1, ei, perm, msgbuf);
  k_node1<<<(2 * NN + B - 1) / B, B, 0, stream>>>(r1pre, msgbuf, off, deg, Wl, bl, Wr, br, xl, xr);
  k_gather_xls<<<(4 * NE + B - 1) / B, B, 0, stream>>>(ei, slot, xl, xls);
  k_gat_node<<<(4 * NN + B - 1) / B, B, 0, stream>>>(xl, xr, xls, off, deg, att, bias_gat, h0h2);
  k_nnconv_mfma<<<256, 512, 65536, stream>>>(h0h2, ea, Bswz2, ei, perm, msgbuf);
  k_node2<<<(2 * NN + B - 1) / B, B, 0, stream>>>(h0h2, msgbuf, off, deg, root2, bias2, Wlin, blin, out);
}

// Round 10
// 135.454 us; speedup vs baseline: 1.0503x; 1.0007x over previous
//
#include <hip/hip_runtime.h>
#include <hip/hip_bf16.h>
#include <math.h>

#define NN 25000
#define NE 100000
#define NTILES (NE / 16)   // 6250 edge tiles of 16
#define NBN 98             // ceil(NN/256)
#define NBE 391            // ceil(NE/256)
#define NBP 264            // ceil(2*33792/256)
#define NBC 391            // ceil(NE/256)

typedef __attribute__((ext_vector_type(8))) short short8;
typedef __attribute__((ext_vector_type(4))) float f32x4;

// pack 8 fp32 -> short8 of bf16 via HW packed convert (RTNE)
static __device__ __forceinline__ short8 pack_bf8(const float* p) {
  union { short8 s; unsigned int u[4]; } r;
#pragma unroll
  for (int q = 0; q < 4; q++)
    asm("v_cvt_pk_bf16_f32 %0, %1, %2" : "=v"(r.u[q]) : "v"(p[2 * q]), "v"(p[2 * q + 1]));
  return r.s;
}

// ==== zero deg ====
__global__ void __launch_bounds__(256) k_zero(int* __restrict__ deg) {
  int n = blockIdx.x * 256 + threadIdx.x;
  if (n < NN) deg[n] = 0;
}

// ==== fused prep: node encoder | edge encoder | W-pack x2 | degree count ====
__global__ void __launch_bounds__(256) k_prep(
    const float* __restrict__ x, const float* __restrict__ eattr,
    const int* __restrict__ ei,
    const float* __restrict__ We_node, const float* __restrict__ be_node,
    const float* __restrict__ We_edge, const float* __restrict__ be_edge,
    const float* __restrict__ root1, const float* __restrict__ bias1,
    const float* __restrict__ W1, const float* __restrict__ b1,
    const float* __restrict__ W2, const float* __restrict__ b2,
    float* __restrict__ h0, float* __restrict__ r1pre, float* __restrict__ ea,
    __hip_bfloat16* __restrict__ Bswz1, __hip_bfloat16* __restrict__ Bswz2,
    int* __restrict__ deg) {
  int b = blockIdx.x;
  int tid = threadIdx.x;
  if (b < NBN) {
    int n = b * 256 + tid;
    if (n >= NN) return;
    float xv[32], hv[32], rv[32];
#pragma unroll
    for (int i = 0; i < 8; i++) *(float4*)(xv + 4 * i) = *(const float4*)(x + n * 32 + 4 * i);
#pragma unroll
    for (int j = 0; j < 32; j++) hv[j] = be_node[j];
#pragma unroll
    for (int i = 0; i < 32; i++) {
      float xi = xv[i];
#pragma unroll
      for (int j = 0; j < 32; j++) hv[j] += xi * We_node[i * 32 + j];
    }
#pragma unroll
    for (int i = 0; i < 8; i++) *(float4*)(h0 + n * 32 + 4 * i) = *(float4*)(hv + 4 * i);
#pragma unroll
    for (int j = 0; j < 32; j++) rv[j] = bias1[j];
#pragma unroll
    for (int i = 0; i < 32; i++) {
      float hi = hv[i];
#pragma unroll
      for (int j = 0; j < 32; j++) rv[j] += hi * root1[i * 32 + j];
    }
#pragma unroll
    for (int i = 0; i < 8; i++) *(float4*)(r1pre + n * 32 + 4 * i) = *(float4*)(rv + 4 * i);
  } else if (b < NBN + NBE) {
    int e = (b - NBN) * 256 + tid;
    if (e >= NE) return;
    float av[16], ov[32];
#pragma unroll
    for (int i = 0; i < 4; i++) *(float4*)(av + 4 * i) = *(const float4*)(eattr + e * 16 + 4 * i);
#pragma unroll
    for (int j = 0; j < 32; j++) ov[j] = be_edge[j];
#pragma unroll
    for (int k = 0; k < 16; k++) {
      float ak = av[k];
#pragma unroll
      for (int j = 0; j < 32; j++) ov[j] += ak * We_edge[k * 32 + j];
    }
#pragma unroll
    for (int i = 0; i < 8; i++) *(float4*)(ea + e * 32 + 4 * i) = *(float4*)(ov + 4 * i);
  } else if (b < NBN + NBE + NBP) {
    int idx = (b - NBN - NBE) * 256 + tid;
    if (idx >= 2 * 33792) return;
    int sel = idx >= 33792;
    int r = idx - sel * 33792;
    int j = r & 7;
    int l = (r >> 3) & 63;
    int nt = (r >> 9) & 1;
    int t = r >> 10;
    int i = 8 * (l >> 4) + j;
    int o = nt * 16 + (l & 15);
    const float* W = sel ? W2 : W1;
    const float* bb = sel ? b2 : b1;
    float v = (t < 32) ? W[t * 1024 + i * 32 + o] : bb[i * 32 + o];
    (sel ? Bswz2 : Bswz1)[r] = __float2bfloat16(v);
  } else {
    int e = (b - NBN - NBE - NBP) * 256 + tid;
    if (e < NE) atomicAdd(&deg[ei[NE + e]], 1);
  }
}

// ==== scan stage 1: per-block sums of deg ====
__global__ void __launch_bounds__(256) k_scan1(const int* __restrict__ deg,
                                               int* __restrict__ bsum) {
  __shared__ int s[256];
  int tid = threadIdx.x;
  int n = blockIdx.x * 256 + tid;
  s[tid] = (n < NN) ? deg[n] : 0;
  __syncthreads();
  for (int d = 128; d > 0; d >>= 1) {
    if (tid < d) s[tid] += s[tid + d];
    __syncthreads();
  }
  if (tid == 0) bsum[blockIdx.x] = s[0];
}

// ==== scan stage 2: block-local exclusive scan + bsum prefix -> off/cursor ===
__global__ void __launch_bounds__(256) k_scan3(const int* __restrict__ deg,
                                               const int* __restrict__ bsum,
                                               int* __restrict__ off,
                                               int* __restrict__ cursor) {
  __shared__ int sb[128];
  __shared__ int s[256];
  int tid = threadIdx.x;
  if (tid < 128) sb[tid] = (tid < NBN) ? bsum[tid] : 0;
  int n = blockIdx.x * 256 + tid;
  int v = (n < NN) ? deg[n] : 0;
  s[tid] = v;
  __syncthreads();
  for (int d = 1; d < 128; d <<= 1) {
    int t = 0;
    if (tid < 128 && tid >= d) t = sb[tid - d];
    __syncthreads();
    if (tid < 128) sb[tid] += t;
    __syncthreads();
  }
  for (int d = 1; d < 256; d <<= 1) {
    int t = (tid >= d) ? s[tid - d] : 0;
    __syncthreads();
    s[tid] += t;
    __syncthreads();
  }
  int base = (blockIdx.x > 0) ? sb[blockIdx.x - 1] : 0;
  int excl = s[tid] - v + base;
  if (n < NN) { off[n] = excl; cursor[n] = excl; }
}

// ==== CSR fill: slot (csr->edge) and perm (edge->csr) ====
__global__ void k_csr_fill(const int* __restrict__ ei, int* __restrict__ cursor,
                           int* __restrict__ slot, int* __restrict__ perm) {
  int e = blockIdx.x * blockDim.x + threadIdx.x;
  if (e >= NE) return;
  int d = ei[NE + e];
  int p = atomicAdd(&cursor[d], 1);
  slot[p] = e;
  perm[e] = p;
}

// ---- NNConv as MFMA GEMM, split-K by block parity ---------------------------
// even blocks: K-steps t=0..15 -> msgA. odd blocks: t=16..31 + bias -> msgB.
// LDS 34 KB -> 4 blocks/CU (16 waves/CU); per-wave chain halved vs full-K.
__global__ void __launch_bounds__(256) k_nnconv_mfma(
    const float* __restrict__ hin, const float* __restrict__ ea,
    const __hip_bfloat16* __restrict__ Bswz, const int* __restrict__ ei,
    const int* __restrict__ perm,
    float* __restrict__ msgA, float* __restrict__ msgB) {
  extern __shared__ short8 bsh[];   // up to 17 steps * 2 ntiles * 64 lanes
  int tid = threadIdx.x;
  int half = blockIdx.x & 1;
  {
    uint4* s4 = (uint4*)bsh;
    const uint4* g4 = (const uint4*)Bswz + (half ? 2048 : 0);
    int cnt = half ? 2176 : 2048;   // 17 or 16 steps x 128 short8
#pragma unroll
    for (int it = 0; it < 9; it++) {
      int idx = tid + 256 * it;
      if (idx < cnt) s4[idx] = g4[idx];
    }
  }
  __syncthreads();

  int wid = tid >> 6;
  int lane = tid & 63;
  int lrow = lane & 15;        // A row / C col
  int lk8 = (lane >> 4) * 8;   // k-offset of this lane's 8 A elems
  float* msgout = half ? msgB : msgA;
  int ebase = half ? 16 : 0;
  int wstride = (gridDim.x >> 1) * 4;

  for (int tile = (blockIdx.x >> 1) * 4 + wid; tile < NTILES; tile += wstride) {
    int e0 = tile * 16;
    int e = e0 + lrow;
    int src = ei[e];
    float hf[8];
    *(float4*)(hf)     = *(const float4*)(hin + src * 32 + lk8);
    *(float4*)(hf + 4) = *(const float4*)(hin + src * 32 + lk8 + 4);
    float eav[16];
#pragma unroll
    for (int c = 0; c < 4; c++)
      *(float4*)(eav + 4 * c) = *(const float4*)(ea + e * 32 + ebase + 4 * c);

    f32x4 a00 = {0.f, 0.f, 0.f, 0.f}, a01 = a00, a10 = a00, a11 = a00;
#pragma unroll
    for (int s = 0; s < 16; s++) {
      float et = eav[s];
      float pr[8];
#pragma unroll
      for (int j = 0; j < 8; j++) pr[j] = et * hf[j];
      short8 af = pack_bf8(pr);
      short8 b0 = bsh[(s * 2 + 0) * 64 + lane];
      short8 b1 = bsh[(s * 2 + 1) * 64 + lane];
      if (s & 1) {
        a01 = __builtin_amdgcn_mfma_f32_16x16x32_bf16(af, b0, a01, 0, 0, 0);
        a11 = __builtin_amdgcn_mfma_f32_16x16x32_bf16(af, b1, a11, 0, 0, 0);
      } else {
        a00 = __builtin_amdgcn_mfma_f32_16x16x32_bf16(af, b0, a00, 0, 0, 0);
        a10 = __builtin_amdgcn_mfma_f32_16x16x32_bf16(af, b1, a10, 0, 0, 0);
      }
    }
    if (half) {  // bias K-step: A = h itself, B staged at local step 16
      short8 af = pack_bf8(hf);
      short8 b0 = bsh[(16 * 2 + 0) * 64 + lane];
      short8 b1 = bsh[(16 * 2 + 1) * 64 + lane];
      a00 = __builtin_amdgcn_mfma_f32_16x16x32_bf16(af, b0, a00, 0, 0, 0);
      a10 = __builtin_amdgcn_mfma_f32_16x16x32_bf16(af, b1, a10, 0, 0, 0);
    }
    f32x4 c0 = a00 + a01;
    f32x4 c1 = a10 + a11;
    int r0 = (lane >> 4) * 4;
#pragma unroll
    for (int r = 0; r < 4; r++) {
      int p = perm[e0 + r0 + r];
      float* mp = msgout + p * 32 + lrow;
      mp[0]  = c0[r];
      mp[16] = c1[r];
    }
  }
}

// ---- node pass 1 (2 threads/node): stream msgA+msgB, pair-exchange, GEMM ----
__global__ void __launch_bounds__(256) k_node1(
    const float* __restrict__ r1pre,
    const float* __restrict__ msgA, const float* __restrict__ msgB,
    const int* __restrict__ off, const int* __restrict__ deg,
    const float* __restrict__ Wl, const float* __restrict__ bl,
    const float* __restrict__ Wr, const float* __restrict__ br,
    float* __restrict__ xl, float* __restrict__ xr) {
  int t = blockIdx.x * blockDim.x + threadIdx.x;
  if (t >= 2 * NN) return;
  int n = t >> 1, half = t & 1;
  int c0 = half * 16;
  float hv[16];
  const float* rp = r1pre + n * 32 + c0;
#pragma unroll
  for (int i = 0; i < 4; i++) *(float4*)(hv + 4 * i) = *(const float4*)(rp + 4 * i);
  int o0 = off[n], o1 = o0 + deg[n];
  for (int idx = o0; idx < o1; idx++) {
    const float* mp = msgA + idx * 32 + c0;
    const float* mq = msgB + idx * 32 + c0;
#pragma unroll
    for (int i = 0; i < 4; i++) {
      float4 mv = *(const float4*)(mp + 4 * i);
      float4 nv = *(const float4*)(mq + 4 * i);
      hv[4 * i + 0] += mv.x + nv.x; hv[4 * i + 1] += mv.y + nv.y;
      hv[4 * i + 2] += mv.z + nv.z; hv[4 * i + 3] += mv.w + nv.w;
    }
  }
#pragma unroll
  for (int j = 0; j < 16; j++) hv[j] = fmaxf(hv[j], 0.f);
  float a0[16], a1[16];
#pragma unroll
  for (int j = 0; j < 16; j++) {
    float o = __shfl_xor(hv[j], 1);
    a0[j] = half ? o : hv[j];
    a1[j] = half ? hv[j] : o;
  }
  const float* W = half ? Wr : Wl;
  const float* bb = half ? br : bl;
  float ov[32];
#pragma unroll
  for (int j = 0; j < 32; j++) ov[j] = bb[j];
#pragma unroll
  for (int i = 0; i < 16; i++) {
    float u = a0[i], v = a1[i];
#pragma unroll
    for (int j = 0; j < 32; j++)
      ov[j] += u * W[i * 32 + j] + v * W[(16 + i) * 32 + j];
  }
  float* dst = (half ? xr : xl) + n * 32;
#pragma unroll
  for (int i = 0; i < 8; i++) *(float4*)(dst + 4 * i) = *(float4*)(ov + 4 * i);
}

// ---- gather xl into CSR order (4 threads/edge, coalesced) -------------------
__global__ void __launch_bounds__(256) k_gather_xls(
    const int* __restrict__ ei, const int* __restrict__ slot,
    const float* __restrict__ xl, float* __restrict__ xls) {
  int t = blockIdx.x * 256 + threadIdx.x;
  if (t >= 4 * NE) return;
  int idx = t >> 2, q = t & 3;
  int s = ei[slot[idx]];
  const float* sp = xl + s * 32 + q * 8;
  float* dp = xls + idx * 32 + q * 8;
  float4 v0 = *(const float4*)(sp);
  float4 v1 = *(const float4*)(sp + 4);
  *(float4*)(dp) = v0;
  *(float4*)(dp + 4) = v1;
}

// ---- GAT node pass (4 threads/node = 1/head): streams xls -------------------
__global__ void __launch_bounds__(256) k_gat_node(
    const float* __restrict__ xl, const float* __restrict__ xr,
    const float* __restrict__ xls,
    const int* __restrict__ off, const int* __restrict__ deg,
    const float* __restrict__ att, const float* __restrict__ bias_gat,
    float* __restrict__ h2) {
  int t = blockIdx.x * blockDim.x + threadIdx.x;
  if (t >= 4 * NN) return;
  int n = t >> 2, hh = t & 3;
  const float* xrp = xr + n * 32 + hh * 8;
  const float* xsp = xl + n * 32 + hh * 8;
  const float* atp = att + hh * 8;
  float xrv[8], attv[8], xself[8];
  *(float4*)(xrv)      = *(const float4*)(xrp);
  *(float4*)(xrv + 4)  = *(const float4*)(xrp + 4);
  *(float4*)(attv)     = *(const float4*)(atp);
  *(float4*)(attv + 4) = *(const float4*)(atp + 4);
  *(float4*)(xself)    = *(const float4*)(xsp);
  *(float4*)(xself + 4)= *(const float4*)(xsp + 4);
  float slg = 0.f;
#pragma unroll
  for (int dg = 0; dg < 8; dg++) {
    float v = xself[dg] + xrv[dg];
    v = (v > 0.f) ? v : 0.2f * v;
    slg += v * attv[dg];
  }
  float mx = slg;
  int o0 = off[n], o1 = o0 + deg[n];
  for (int idx = o0; idx < o1; idx++) {
    const float* xp = xls + idx * 32 + hh * 8;
    float xv[8];
    *(float4*)(xv)     = *(const float4*)(xp);
    *(float4*)(xv + 4) = *(const float4*)(xp + 4);
    float lg = 0.f;
#pragma unroll
    for (int dg = 0; dg < 8; dg++) {
      float v = xv[dg] + xrv[dg];
      v = (v > 0.f) ? v : 0.2f * v;
      lg += v * attv[dg];
    }
    mx = fmaxf(mx, lg);
  }
  float a = __expf(slg - mx);
  float den = a;
  float accv[8];
#pragma unroll
  for (int dg = 0; dg < 8; dg++) accv[dg] = a * xself[dg];
  for (int idx = o0; idx < o1; idx++) {
    const float* xp = xls + idx * 32 + hh * 8;
    float xv[8];
    *(float4*)(xv)     = *(const float4*)(xp);
    *(float4*)(xv + 4) = *(const float4*)(xp + 4);
    float lg = 0.f;
#pragma unroll
    for (int dg = 0; dg < 8; dg++) {
      float v = xv[dg] + xrv[dg];
      v = (v > 0.f) ? v : 0.2f * v;
      lg += v * attv[dg];
    }
    float w = __expf(lg - mx);
    den += w;
#pragma unroll
    for (int dg = 0; dg < 8; dg++) accv[dg] += w * xv[dg];
  }
  float sc = 1.f / (den + 1e-16f);
  float hv[8];
#pragma unroll
  for (int dg = 0; dg < 8; dg++)
    hv[dg] = fmaxf(accv[dg] * sc + bias_gat[hh * 8 + dg], 0.f);
  float* op = h2 + n * 32 + hh * 8;
  *(float4*)(op)     = *(float4*)(hv);
  *(float4*)(op + 4) = *(float4*)(hv + 4);
}

// ---- node pass 2 (2 threads/node): root2 half-GEMM + stream + classifier ----
__global__ void __launch_bounds__(256) k_node2(
    const float* __restrict__ h2,
    const float* __restrict__ msgA, const float* __restrict__ msgB,
    const int* __restrict__ off, const int* __restrict__ deg,
    const float* __restrict__ root2, const float* __restrict__ bias2,
    const float* __restrict__ Wlin, const float* __restrict__ blin,
    float* __restrict__ out) {
  int t = blockIdx.x * blockDim.x + threadIdx.x;
  if (t >= 2 * NN) return;
  int n = t >> 1, half = t & 1;
  int c0 = half * 16;
  float h2v[32];
#pragma unroll
  for (int i = 0; i < 8; i++) *(float4*)(h2v + 4 * i) = *(const float4*)(h2 + n * 32 + 4 * i);
  float rv[16];
#pragma unroll
  for (int j = 0; j < 16; j++) rv[j] = bias2[c0 + j];
#pragma unroll
  for (int i = 0; i < 32; i++) {
    float hi = h2v[i];
#pragma unroll
    for (int j = 0; j < 16; j++) rv[j] += hi * root2[i * 32 + c0 + j];
  }
  int o0 = off[n], o1 = o0 + deg[n];
  for (int idx = o0; idx < o1; idx++) {
    const float* mp = msgA + idx * 32 + c0;
    const float* mq = msgB + idx * 32 + c0;
#pragma unroll
    for (int i = 0; i < 4; i++) {
      float4 mv = *(const float4*)(mp + 4 * i);
      float4 nv = *(const float4*)(mq + 4 * i);
      rv[4 * i + 0] += mv.x + nv.x; rv[4 * i + 1] += mv.y + nv.y;
      rv[4 * i + 2] += mv.z + nv.z; rv[4 * i + 3] += mv.w + nv.w;
    }
  }
#pragma unroll
  for (int j = 0; j < 16; j++) rv[j] = fmaxf(rv[j], 0.f);
  float ov[10];
#pragma unroll
  for (int c = 0; c < 10; c++) ov[c] = 0.f;
#pragma unroll
  for (int j = 0; j < 16; j++) {
    float hj = rv[j];
#pragma unroll
    for (int c = 0; c < 10; c++) ov[c] += hj * Wlin[(c0 + j) * 10 + c];
  }
#pragma unroll
  for (int c = 0; c < 10; c++) ov[c] += __shfl_xor(ov[c], 1);
  if (half == 0) {
#pragma unroll
    for (int c = 0; c < 5; c++) out[n * 10 + c] = ov[c] + blin[c];
  } else {
#pragma unroll
    for (int c = 5; c < 10; c++) out[n * 10 + c] = ov[c] + blin[c];
  }
}

extern "C" void kernel_launch(void* const* d_in, const int* in_sizes, int n_in,
                              void* d_out, int out_size, void* d_ws, size_t ws_size,
                              hipStream_t stream) {
  const float* x         = (const float*)d_in[0];
  const float* edge_attr = (const float*)d_in[1];
  const int*   ei        = (const int*)d_in[2];   // [2,E]: src = ei, dst = ei+NE
  const float* We_node   = (const float*)d_in[3];
  const float* be_node   = (const float*)d_in[4];
  const float* We_edge   = (const float*)d_in[5];
  const float* be_edge   = (const float*)d_in[6];
  const float* W1_nn     = (const float*)d_in[7];
  const float* b1_nn     = (const float*)d_in[8];
  const float* root1     = (const float*)d_in[9];
  const float* bias1     = (const float*)d_in[10];
  const float* Wl        = (const float*)d_in[11];
  const float* bl        = (const float*)d_in[12];
  const float* Wr        = (const float*)d_in[13];
  const float* br        = (const float*)d_in[14];
  const float* att       = (const float*)d_in[15];
  const float* bias_gat  = (const float*)d_in[16];
  const float* W2_nn     = (const float*)d_in[17];
  const float* b2_nn     = (const float*)d_in[18];
  const float* root2     = (const float*)d_in[19];
  const float* bias2     = (const float*)d_in[20];
  const float* Wlin      = (const float*)d_in[21];
  const float* blin      = (const float*)d_in[22];
  float* out = (float*)d_out;

  float* ws = (float*)d_ws;
  float* h0h2  = ws;                 // NN*32 (h0, later h2)
  float* ea    = h0h2 + NN * 32;     // NE*32
  float* r1pre = ea + NE * 32;       // NN*32
  float* xl    = r1pre + NN * 32;    // NN*32
  float* xr    = xl + NN * 32;       // NN*32
  float* msgA  = xr + NN * 32;       // NE*32 (CSR order, K-half 0)
  float* msgB  = msgA + NE * 32;     // NE*32 (CSR order, K-half 1 + bias)
  float* xls   = msgB + NE * 32;     // NE*32 (xl gathered to CSR order)
  float* fend  = xls + NE * 32;
  __hip_bfloat16* Bswz1 = (__hip_bfloat16*)fend;            // 33792 bf16
  __hip_bfloat16* Bswz2 = (__hip_bfloat16*)(fend + 17000);  // 33792 bf16
  int* deg    = (int*)(fend + 34000);   // NN
  int* off    = deg + NN;               // NN
  int* cursor = off + NN;               // NN
  int* bsum   = cursor + NN;            // 128
  int* slot   = bsum + 128;             // NE
  int* perm   = slot + NE;              // NE

  const int B = 256;
  k_zero<<<NBN, B, 0, stream>>>(deg);
  k_prep<<<NBN + NBE + NBP + NBC, B, 0, stream>>>(
      x, edge_attr, ei, We_node, be_node, We_edge, be_edge, root1, bias1,
      W1_nn, b1_nn, W2_nn, b2_nn, h0h2, r1pre, ea, Bswz1, Bswz2, deg);
  k_scan1<<<NBN, B, 0, stream>>>(deg, bsum);
  k_scan3<<<NBN, B, 0, stream>>>(deg, bsum, off, cursor);
  k_csr_fill<<<(NE + B - 1) / B, B, 0, stream>>>(ei, cursor, slot, perm);
  k_nnconv_mfma<<<1024, B, 34816, stream>>>(h0h2, ea, Bswz1, ei, perm, msgA, msgB);
  k_node1<<<(2 * NN + B - 1) / B, B, 0, stream>>>(r1pre, msgA, msgB, off, deg, Wl, bl, Wr, br, xl, xr);
  k_gather_xls<<<(4 * NE + B - 1) / B, B, 0, stream>>>(ei, slot, xl, xls);
  k_gat_node<<<(4 * NN + B - 1) / B, B, 0, stream>>>(xl, xr, xls, off, deg, att, bias_gat, h0h2);
  k_nnconv_mfma<<<1024, B, 34816, stream>>>(h0h2, ea, Bswz2, ei, perm, msgA, msgB);
  k_node2<<<(2 * NN + B - 1) / B, B, 0, stream>>>(h0h2, msgA, msgB, off, deg, root2, bias2, Wlin, blin, out);
}